// Round 7
// baseline (7489.893 us; speedup 1.0000x reference)
//
#include <hip/hip_runtime.h>
#include <hip/hip_bf16.h>
#include <stdint.h>

typedef __attribute__((ext_vector_type(8))) short short8;
typedef __attribute__((ext_vector_type(4))) float f32x4;
typedef __attribute__((ext_vector_type(4))) unsigned int u32x4;
typedef __attribute__((ext_vector_type(2))) unsigned int u32x2;

#define B_SZ 256
#define T_SZ 2048
#define DX 32
#define DY 16
#define DH 512
#define KX 256   // D_I * d_x
#define KY 128   // D_O * d_y
#define STEPS 2040
#define SCALE 2.8853900817779268f   // 2*log2(e), folded into W1/b1 so tanh skips a mul

__device__ __forceinline__ unsigned short f2bf(float f) {
    unsigned int u = __float_as_uint(f);
    u += 0x7FFFu + ((u >> 16) & 1u);   // RNE
    return (unsigned short)(u >> 16);
}
__device__ __forceinline__ float bf2f(unsigned short h) {
    return __uint_as_float(((unsigned int)h) << 16);
}
// compiler-generated packed f32->bf16 (RNE) — no hand-written asm (m240)
__device__ __forceinline__ unsigned int pk_bf16(float lo, float hi) {
    __hip_bfloat162 v = __float22bfloat162_rn(make_float2(lo, hi));
    unsigned int r;
    __builtin_memcpy(&r, &v, 4);
    return r;
}
// input pre-scaled by 2*log2e: tanh(x) = 1 - 2/(exp2(s)+1)
__device__ __forceinline__ float tanh_fast(float s) {
    float e = __builtin_amdgcn_exp2f(s);
    float r = __builtin_amdgcn_rcpf(e + 1.0f);
    return __builtin_fmaf(-2.0f, r, 1.0f);
}

// ---- W1x transpose+convert+scale: w1xt[n][k] = bf16(S*W1[k][n]) ----------
__global__ void k_w1xt(const float* __restrict__ W1, unsigned short* __restrict__ w1xt) {
    int k = blockIdx.x;
    for (int h = 0; h < 2; ++h) {
        int n = threadIdx.x + h * 256;
        w1xt[(size_t)n * KX + k] = f2bf(W1[(size_t)k * DH + n] * SCALE);
    }
}

// ---- pre[b][t_rel][n] = bf16( S*(x[b,t:t+8,:]flat . W1x[:,n] + b1[n]) ) --
__global__ __launch_bounds__(256, 2) void k_pre(
    const float* __restrict__ x, const unsigned short* __restrict__ w1xt,
    const float* __restrict__ b1, unsigned short* __restrict__ pre,
    int t_base, int Tc)
{
    __shared__ __align__(16) unsigned short xl[264 * 40];
    __shared__ __align__(16) unsigned short bl[64 * 256];
    const int tid = threadIdx.x;
    const int b = blockIdx.z;
    const int t0_rel = blockIdx.x * 256;
    const int n0 = blockIdx.y * 64;

    for (int idx = tid; idx < 264 * 2; idx += 256) {
        int r = idx >> 1, half = idx & 1;
        int t = t_base + t0_rel + r; if (t > T_SZ - 1) t = T_SZ - 1;
        const float* src = x + ((size_t)b * T_SZ + t) * DX + half * 16;
        unsigned int u[8];
        #pragma unroll
        for (int q = 0; q < 4; ++q) {
            float4 v = *(const float4*)(src + q * 4);
            u[2*q]   = pk_bf16(v.x, v.y);
            u[2*q+1] = pk_bf16(v.z, v.w);
        }
        u32x4 w0 = {u[0], u[1], u[2], u[3]};
        u32x4 w1 = {u[4], u[5], u[6], u[7]};
        *(u32x4*)&xl[r * 40 + half * 16]     = w0;
        *(u32x4*)&xl[r * 40 + half * 16 + 8] = w1;
    }
    for (int idx = tid; idx < 64 * 32; idx += 256) {
        int n = idx >> 5, c = idx & 31;
        u32x4 v = *(const u32x4*)&w1xt[(size_t)(n0 + n) * KX + c * 8];
        *(u32x4*)&bl[n * 256 + ((c ^ (n & 7))) * 8] = v;
    }
    const int l = tid & 63, w = tid >> 6;
    const int m = l & 15, g = l >> 4;
    const int wm = w >> 1, wn = w & 1;
    float b1v[2];
    #pragma unroll
    for (int nt = 0; nt < 2; ++nt) b1v[nt] = b1[n0 + wn * 32 + nt * 16 + m] * SCALE;
    __syncthreads();

    f32x4 acc[8][2];
    #pragma unroll
    for (int mt = 0; mt < 8; ++mt)
        #pragma unroll
        for (int nt = 0; nt < 2; ++nt) { f32x4 z = {0,0,0,0}; acc[mt][nt] = z; }

    #pragma unroll
    for (int ks = 0; ks < 8; ++ks) {
        short8 bfr[2];
        #pragma unroll
        for (int nt = 0; nt < 2; ++nt) {
            int nl = wn * 32 + nt * 16 + m;
            bfr[nt] = *(const short8*)&bl[nl * 256 + ((ks * 4 + g) ^ (nl & 7)) * 8];
        }
        #pragma unroll
        for (int mt = 0; mt < 8; ++mt) {
            int rowt = wm * 128 + mt * 16 + m;
            short8 afr = *(const short8*)&xl[(rowt + ks) * 40 + g * 8];
            #pragma unroll
            for (int nt = 0; nt < 2; ++nt)
                acc[mt][nt] = __builtin_amdgcn_mfma_f32_16x16x32_bf16(afr, bfr[nt], acc[mt][nt], 0, 0, 0);
        }
    }
    #pragma unroll
    for (int mt = 0; mt < 8; ++mt) {
        #pragma unroll
        for (int nt = 0; nt < 2; ++nt) {
            int n_g = n0 + wn * 32 + nt * 16 + m;
            #pragma unroll
            for (int r = 0; r < 4; ++r) {
                int t_rel = t0_rel + wm * 128 + mt * 16 + g * 4 + r;
                if (t_rel < Tc)
                    pre[((size_t)b * Tc + t_rel) * DH + n_g] = f2bf(acc[mt][nt][r] + b1v[nt]);
            }
        }
    }
}

// ---- sequential NARX: 16 blocks x 16 batch rows, 512 thr (8 waves x 64 hid)
// SINGLE barrier per step: carry ring in registers (r2-verified cndmask logic);
// cross-wave out reduce via ds_add_f32 into 4-rotating padded LDS accumulators;
// consumers finish (bias+pack+insert+store) post-barrier; rolling 1-step prefetch.
__global__ __launch_bounds__(512, 1) void k_seq(
    const float* __restrict__ W1, const float* __restrict__ W2,
    const float* __restrict__ b2, const unsigned short* __restrict__ pre,
    unsigned int* __restrict__ carrybuf, float* __restrict__ out,
    int t_base, int Tc)
{
    __shared__ __align__(16) unsigned short hl[8 * 16 * 72];  // [wave][batch][64+8pad]
    __shared__ __align__(16) float yb4[4][16][20];            // [rot][batch][o + 4pad]
    const int tid = threadIdx.x;
    const int l = tid & 63, w = tid >> 6;
    const int m = l & 15, g = l >> 4, gh = g & 1;
    const int rb = blockIdx.x * 16;
    const int hb = w * 64;

    // static A-frags of S*W1y^T: A[row=hidden][k], k = lag*16+f
    short8 aw1y[4][4];
    #pragma unroll
    for (int mt = 0; mt < 4; ++mt)
        #pragma unroll
        for (int ks = 0; ks < 4; ++ks) {
            short8 f;
            #pragma unroll
            for (int j = 0; j < 8; ++j)
                f[j] = (short)f2bf(W1[(size_t)(KX + ks * 32 + g * 8 + j) * DH + hb + mt * 16 + m] * SCALE);
            aw1y[mt][ks] = f;
        }
    // static B-frags of W2: B[k=hidden][col=o] (NOT scaled)
    short8 bw2[2];
    #pragma unroll
    for (int k2 = 0; k2 < 2; ++k2) {
        short8 f;
        #pragma unroll
        for (int j = 0; j < 8; ++j)
            f[j] = (short)f2bf(W2[(size_t)(hb + k2 * 32 + g * 8 + j) * DY + m]);
        bw2[k2] = f;
    }
    float b2v[8];
    #pragma unroll
    for (int j = 0; j < 8; ++j) b2v[j] = b2[gh * 8 + j];

    // carry ring: creg[i] holds slot ((i + (g>>1)) & 7)'s slice
    // carry[slot][m][gh*8 + j], j=0..7 (the MFMA B-frag dwords) — r2-verified
    u32x4 creg[8];
    if (t_base == 0) {
        #pragma unroll
        for (int i = 0; i < 8; ++i) creg[i] = (u32x4){0u, 0u, 0u, 0u};
        for (int i = tid; i < 2048; i += 512) {   // zero y_pred[:, 0:8, :]
            int b_ = i >> 7, rem = i & 127, tt = rem >> 4, o = rem & 15;
            out[((size_t)(rb + b_) * T_SZ + tt) * DY + o] = 0.0f;
        }
    } else {
        const u32x4* src = (const u32x4*)carrybuf + ((size_t)blockIdx.x * 64 + l) * 8;
        #pragma unroll
        for (int i = 0; i < 8; ++i) creg[i] = src[i];
    }
    for (int i = tid; i < 4 * 16 * 20; i += 512) ((float*)yb4)[i] = 0.0f;
    __syncthreads();

    const unsigned short* prep = pre + ((size_t)(rb + m) * Tc) * DH + hb + g * 4;
    u32x2 pf[2][4];
    #pragma unroll
    for (int mt = 0; mt < 4; ++mt) pf[0][mt] = *(const u32x2*)(prep + mt * 16);

    for (int t = 0; t < Tc; t += 8) {
        #pragma unroll
        for (int c = 0; c < 8; ++c) {           // phase c == t_abs & 7
            const int ta = t + c;
            // ---- finish step ta-1 (post-barrier consumer work) ----
            if (c != 0 || t != 0) {
                const int pb = (c + 3) & 3;     // buffer added in previous region
                f32x4 ylo = *(const f32x4*)&yb4[pb][m][gh * 8];
                f32x4 yhi = *(const f32x4*)&yb4[pb][m][gh * 8 + 4];
                #pragma unroll
                for (int j = 0; j < 4; ++j) { ylo[j] += b2v[j]; yhi[j] += b2v[j + 4]; }
                if (g < 2) {                    // g=0/1 cover all (m, o); g=2/3 duplicates
                    float* op = out + ((size_t)(rb + m) * T_SZ + (t_base + ta + 7)) * DY + gh * 8;
                    float4 s0 = {ylo[0], ylo[1], ylo[2], ylo[3]};
                    float4 s1 = {yhi[0], yhi[1], yhi[2], yhi[3]};
                    *(float4*)op       = s0;    // hidden by this step's compute
                    *(float4*)(op + 4) = s1;
                }
                u32x4 yb = { pk_bf16(ylo[0], ylo[1]), pk_bf16(ylo[2], ylo[3]),
                             pk_bf16(yhi[0], yhi[1]), pk_bf16(yhi[2], yhi[3]) };
                const bool glo = (g < 2);       // r2-verified ring insert
                u32x4 o1 = creg[(c + 7) & 7], o2 = creg[(c + 6) & 7];
                creg[(c + 7) & 7] = glo ? yb : o1;
                creg[(c + 6) & 7] = glo ? o2 : yb;
            }
            // ---- zero rotation: buf (c+2)&3 (read 1 region ago, added 2 ahead) ----
            if (tid < 160)
                *(u32x2*)(((float*)yb4[(c + 2) & 3]) + tid * 2) = (u32x2){0u, 0u};
            // ---- rolling prefetch of pre for step ta+1 ----
            if (ta + 1 < Tc) {
                const unsigned short* p2 = prep + (size_t)(ta + 1) * DH;
                #pragma unroll
                for (int mt = 0; mt < 4; ++mt) pf[(c + 1) & 1][mt] = *(const u32x2*)(p2 + mt * 16);
            }
            // ---- y-GEMM from register carry; acc init from prefetched pre ----
            f32x4 acc[4];
            #pragma unroll
            for (int mt = 0; mt < 4; ++mt) {
                acc[mt][0] = bf2f((unsigned short)(pf[c & 1][mt].x & 0xFFFFu));
                acc[mt][1] = bf2f((unsigned short)(pf[c & 1][mt].x >> 16));
                acc[mt][2] = bf2f((unsigned short)(pf[c & 1][mt].y & 0xFFFFu));
                acc[mt][3] = bf2f((unsigned short)(pf[c & 1][mt].y >> 16));
            }
            #pragma unroll
            for (int mt = 0; mt < 4; ++mt)
                #pragma unroll
                for (int ks = 0; ks < 4; ++ks)
                    acc[mt] = __builtin_amdgcn_mfma_f32_16x16x32_bf16(
                        aw1y[mt][ks], __builtin_bit_cast(short8, creg[(c + 2 * ks) & 7]),
                        acc[mt], 0, 0, 0);
            // ---- tanh + pack + hl bounce (own-wave region, no barrier) ----
            #pragma unroll
            for (int mt = 0; mt < 4; ++mt) {
                float h0 = tanh_fast(acc[mt][0]);
                float h1 = tanh_fast(acc[mt][1]);
                float h2 = tanh_fast(acc[mt][2]);
                float h3 = tanh_fast(acc[mt][3]);
                u32x2 p = {pk_bf16(h0, h1), pk_bf16(h2, h3)};
                *(u32x2*)&hl[w * 1152 + m * 72 + mt * 16 + g * 4] = p;
            }
            // ---- out partial: A = h [batch][k=hid], B = W2 -> [batch=g*4+r][o=m] ----
            f32x4 oacc = {0.f, 0.f, 0.f, 0.f};
            #pragma unroll
            for (int k2 = 0; k2 < 2; ++k2) {
                short8 ha = *(const short8*)&hl[w * 1152 + m * 72 + k2 * 32 + g * 8];
                oacc = __builtin_amdgcn_mfma_f32_16x16x32_bf16(ha, bw2[k2], oacc, 0, 0, 0);
            }
            #pragma unroll
            for (int r = 0; r < 4; ++r)
                (void)__hip_atomic_fetch_add(&yb4[c & 3][g * 4 + r][m], oacc[r],
                                             __ATOMIC_RELAXED, __HIP_MEMORY_SCOPE_WORKGROUP);
            __syncthreads();
        }
    }
    // ---- epilogue: finish final step (phase-0 semantics), persist ring ----
    {
        f32x4 ylo = *(const f32x4*)&yb4[3][m][gh * 8];
        f32x4 yhi = *(const f32x4*)&yb4[3][m][gh * 8 + 4];
        #pragma unroll
        for (int j = 0; j < 4; ++j) { ylo[j] += b2v[j]; yhi[j] += b2v[j + 4]; }
        if (g < 2) {
            float* op = out + ((size_t)(rb + m) * T_SZ + (t_base + Tc + 7)) * DY + gh * 8;
            float4 s0 = {ylo[0], ylo[1], ylo[2], ylo[3]};
            float4 s1 = {yhi[0], yhi[1], yhi[2], yhi[3]};
            *(float4*)op       = s0;
            *(float4*)(op + 4) = s1;
        }
        u32x4 yb = { pk_bf16(ylo[0], ylo[1]), pk_bf16(ylo[2], ylo[3]),
                     pk_bf16(yhi[0], yhi[1]), pk_bf16(yhi[2], yhi[3]) };
        const bool glo = (g < 2);
        u32x4 o1 = creg[7], o2 = creg[6];
        creg[7] = glo ? yb : o1;
        creg[6] = glo ? o2 : yb;
    }
    if (w == 0) {
        u32x4* dst = (u32x4*)carrybuf + ((size_t)blockIdx.x * 64 + l) * 8;
        #pragma unroll
        for (int i = 0; i < 8; ++i) dst[i] = creg[i];
    }
}

extern "C" void kernel_launch(void* const* d_in, const int* in_sizes, int n_in,
                              void* d_out, int out_size, void* d_ws, size_t ws_size,
                              hipStream_t stream) {
    const float* x  = (const float*)d_in[0];
    const float* W1 = (const float*)d_in[1];
    const float* b1 = (const float*)d_in[2];
    const float* W2 = (const float*)d_in[3];
    const float* b2 = (const float*)d_in[4];
    float* out = (float*)d_out;
    char* ws = (char*)d_ws;

    size_t ofs = 0;
    unsigned short* w1xt = (unsigned short*)(ws + ofs); ofs += (size_t)DH * KX * 2;       // 256 KB
    unsigned int* carrybuf = (unsigned int*)(ws + ofs); ofs += (size_t)16 * 64 * 8 * 16;  // 128 KB
    ofs = (ofs + 255) & ~(size_t)255;
    size_t avail = (ws_size > ofs) ? (ws_size - ofs) : 0;
    long chunkT = (long)(avail / ((size_t)B_SZ * DH * 2));
    if (chunkT > 680) chunkT = 680;        // 3 chunks: pre = 178 MB, fits L3 (256 MB)
    chunkT &= ~7L;                         // phases require t_base%8==0, Tc%8==0
    if (chunkT < 8) chunkT = 8;            // assumes ws >= ~2.4 MB
    unsigned short* prebuf = (unsigned short*)(ws + ofs);

    hipLaunchKernelGGL(k_w1xt, dim3(KX), dim3(256), 0, stream, W1, w1xt);
    for (long t0 = 0; t0 < STEPS; t0 += chunkT) {
        int Tc = (int)(((STEPS - t0) < chunkT) ? (STEPS - t0) : chunkT);
        int nbt = (Tc + 255) / 256;
        hipLaunchKernelGGL(k_pre, dim3(nbt, 8, B_SZ), dim3(256), 0, stream,
                           x, w1xt, b1, prebuf, (int)t0, Tc);
        hipLaunchKernelGGL(k_seq, dim3(16), dim3(512), 0, stream,
                           W1, W2, b2, prebuf, carrybuf, out, (int)t0, Tc);
    }
}

// Round 8
// 4195.884 us; speedup vs baseline: 1.7851x; 1.7851x over previous
//
#include <hip/hip_runtime.h>
#include <hip/hip_bf16.h>
#include <stdint.h>

typedef __attribute__((ext_vector_type(8))) short short8;
typedef __attribute__((ext_vector_type(4))) float f32x4;
typedef __attribute__((ext_vector_type(4))) unsigned int u32x4;
typedef __attribute__((ext_vector_type(2))) unsigned int u32x2;

#define B_SZ 256
#define T_SZ 2048
#define DX 32
#define DY 16
#define DH 512
#define KX 256   // D_I * d_x
#define KY 128   // D_O * d_y
#define STEPS 2040
#define SCALE 2.8853900817779268f   // 2*log2(e), folded into W1/b1 so tanh skips a mul

__device__ __forceinline__ unsigned short f2bf(float f) {
    unsigned int u = __float_as_uint(f);
    u += 0x7FFFu + ((u >> 16) & 1u);   // RNE
    return (unsigned short)(u >> 16);
}
__device__ __forceinline__ float bf2f(unsigned short h) {
    return __uint_as_float(((unsigned int)h) << 16);
}
// compiler-generated packed f32->bf16 (RNE) — no hand-written asm (m240)
__device__ __forceinline__ unsigned int pk_bf16(float lo, float hi) {
    __hip_bfloat162 v = __float22bfloat162_rn(make_float2(lo, hi));
    unsigned int r;
    __builtin_memcpy(&r, &v, 4);
    return r;
}
// input pre-scaled by 2*log2e: tanh(x) = 1 - 2/(exp2(s)+1)
__device__ __forceinline__ float tanh_fast(float s) {
    float e = __builtin_amdgcn_exp2f(s);
    float r = __builtin_amdgcn_rcpf(e + 1.0f);
    return __builtin_fmaf(-2.0f, r, 1.0f);
}

// ---- W1x transpose+convert+scale: w1xt[n][k] = bf16(S*W1[k][n]) ----------
__global__ void k_w1xt(const float* __restrict__ W1, unsigned short* __restrict__ w1xt) {
    int k = blockIdx.x;
    for (int h = 0; h < 2; ++h) {
        int n = threadIdx.x + h * 256;
        w1xt[(size_t)n * KX + k] = f2bf(W1[(size_t)k * DH + n] * SCALE);
    }
}

// ---- pre[b][t_rel][n] = bf16( S*(x[b,t:t+8,:]flat . W1x[:,n] + b1[n]) ) --
__global__ __launch_bounds__(256, 2) void k_pre(
    const float* __restrict__ x, const unsigned short* __restrict__ w1xt,
    const float* __restrict__ b1, unsigned short* __restrict__ pre,
    int t_base, int Tc)
{
    __shared__ __align__(16) unsigned short xl[264 * 40];
    __shared__ __align__(16) unsigned short bl[64 * 256];
    const int tid = threadIdx.x;
    const int b = blockIdx.z;
    const int t0_rel = blockIdx.x * 256;
    const int n0 = blockIdx.y * 64;

    for (int idx = tid; idx < 264 * 2; idx += 256) {
        int r = idx >> 1, half = idx & 1;
        int t = t_base + t0_rel + r; if (t > T_SZ - 1) t = T_SZ - 1;
        const float* src = x + ((size_t)b * T_SZ + t) * DX + half * 16;
        unsigned int u[8];
        #pragma unroll
        for (int q = 0; q < 4; ++q) {
            float4 v = *(const float4*)(src + q * 4);
            u[2*q]   = pk_bf16(v.x, v.y);
            u[2*q+1] = pk_bf16(v.z, v.w);
        }
        u32x4 w0 = {u[0], u[1], u[2], u[3]};
        u32x4 w1 = {u[4], u[5], u[6], u[7]};
        *(u32x4*)&xl[r * 40 + half * 16]     = w0;
        *(u32x4*)&xl[r * 40 + half * 16 + 8] = w1;
    }
    for (int idx = tid; idx < 64 * 32; idx += 256) {
        int n = idx >> 5, c = idx & 31;
        u32x4 v = *(const u32x4*)&w1xt[(size_t)(n0 + n) * KX + c * 8];
        *(u32x4*)&bl[n * 256 + ((c ^ (n & 7))) * 8] = v;
    }
    const int l = tid & 63, w = tid >> 6;
    const int m = l & 15, g = l >> 4;
    const int wm = w >> 1, wn = w & 1;
    float b1v[2];
    #pragma unroll
    for (int nt = 0; nt < 2; ++nt) b1v[nt] = b1[n0 + wn * 32 + nt * 16 + m] * SCALE;
    __syncthreads();

    f32x4 acc[8][2];
    #pragma unroll
    for (int mt = 0; mt < 8; ++mt)
        #pragma unroll
        for (int nt = 0; nt < 2; ++nt) { f32x4 z = {0,0,0,0}; acc[mt][nt] = z; }

    #pragma unroll
    for (int ks = 0; ks < 8; ++ks) {
        short8 bfr[2];
        #pragma unroll
        for (int nt = 0; nt < 2; ++nt) {
            int nl = wn * 32 + nt * 16 + m;
            bfr[nt] = *(const short8*)&bl[nl * 256 + ((ks * 4 + g) ^ (nl & 7)) * 8];
        }
        #pragma unroll
        for (int mt = 0; mt < 8; ++mt) {
            int rowt = wm * 128 + mt * 16 + m;
            short8 afr = *(const short8*)&xl[(rowt + ks) * 40 + g * 8];
            #pragma unroll
            for (int nt = 0; nt < 2; ++nt)
                acc[mt][nt] = __builtin_amdgcn_mfma_f32_16x16x32_bf16(afr, bfr[nt], acc[mt][nt], 0, 0, 0);
        }
    }
    #pragma unroll
    for (int mt = 0; mt < 8; ++mt) {
        #pragma unroll
        for (int nt = 0; nt < 2; ++nt) {
            int n_g = n0 + wn * 32 + nt * 16 + m;
            #pragma unroll
            for (int r = 0; r < 4; ++r) {
                int t_rel = t0_rel + wm * 128 + mt * 16 + g * 4 + r;
                if (t_rel < Tc)
                    pre[((size_t)b * Tc + t_rel) * DH + n_g] = f2bf(acc[mt][nt][r] + b1v[nt]);
            }
        }
    }
}

// ---- sequential NARX: 16 blocks x 16 batch rows, 512 thr (8 waves x 64 hid)
// r1 skeleton verbatim (LDS carry ring, per-step rolling prefetch, 4-wave
// reduce direct to carry, two __syncthreads) + yreg batched out-stores (r4,
// neutral) + compiler-path packed bf16 (m240) + SCALE folded into W1/b1.
__global__ __launch_bounds__(512, 1) void k_seq(
    const float* __restrict__ W1, const float* __restrict__ W2,
    const float* __restrict__ b2, const unsigned short* __restrict__ pre,
    unsigned short* __restrict__ carrybf, float* __restrict__ out,
    int t_base, int Tc)
{
    __shared__ __align__(16) unsigned short carry[8 * 16 * 24]; // [slot][batch][16+8pad]
    __shared__ __align__(16) unsigned short hl[8 * 16 * 72];    // [wave][batch][64+8pad]
    __shared__ __align__(16) float ob[8 * 16 * 16];
    const int tid = threadIdx.x;
    const int l = tid & 63, w = tid >> 6;
    const int m = l & 15, g = l >> 4;
    const int rb = blockIdx.x * 16;
    const int hb = w * 64;

    // static A-frags of S*W1y^T: A[row=hidden][k], k = lag*16+f
    short8 aw1y[4][4];
    #pragma unroll
    for (int mt = 0; mt < 4; ++mt)
        #pragma unroll
        for (int ks = 0; ks < 4; ++ks) {
            short8 f;
            #pragma unroll
            for (int j = 0; j < 8; ++j)
                f[j] = (short)f2bf(W1[(size_t)(KX + ks * 32 + g * 8 + j) * DH + hb + mt * 16 + m] * SCALE);
            aw1y[mt][ks] = f;
        }
    // static B-frags of W2: B[k=hidden][col=o]  (NOT scaled)
    short8 bw2[2];
    #pragma unroll
    for (int k2 = 0; k2 < 2; ++k2) {
        short8 f;
        #pragma unroll
        for (int j = 0; j < 8; ++j)
            f[j] = (short)f2bf(W2[(size_t)(hb + k2 * 32 + g * 8 + j) * DY + m]);
        bw2[k2] = f;
    }
    float b2v = b2[tid & 15];

    // carry init (ring buffer keyed on absolute t)
    if (t_base == 0) {
        for (int i = tid; i < 8 * 16 * 24; i += 512) carry[i] = 0;
        for (int i = tid; i < 16 * 8 * 16; i += 512) {   // zero y_pred[:, 0:8, :]
            int bb = i >> 7, rem = i & 127, t = rem >> 4, o = rem & 15;
            out[((size_t)(rb + bb) * T_SZ + t) * DY + o] = 0.0f;
        }
    } else {
        for (int i = tid; i < 2048; i += 512) {
            int slot = i >> 8, rem = i & 255, bb = rem >> 4, f = rem & 15;
            carry[slot * 384 + bb * 24 + f] = carrybf[(size_t)blockIdx.x * 2048 + i];
        }
    }
    __syncthreads();

    const unsigned short* prep = pre + ((size_t)(rb + m) * Tc) * DH + hb + g * 4;
    u32x2 pf[4];
    #pragma unroll
    for (int mt = 0; mt < 4; ++mt) pf[mt] = *(const u32x2*)(prep + mt * 16);

    const int cbase = m * 24 + (g & 1) * 8;
    const int bb = tid >> 4, o = tid & 15;   // reducer mapping (tid<256)
    float yreg[8];

    for (int t = 0; t < Tc; t += 8) {
        #pragma unroll
        for (int c = 0; c < 8; ++c) {           // phase c == t_abs & 7
            const int ta = t + c;
            u32x2 cur[4];
            #pragma unroll
            for (int mt = 0; mt < 4; ++mt) cur[mt] = pf[mt];
            if (ta + 1 < Tc) {   // rolling prefetch of next step's pre (r1-proven)
                const unsigned short* p2 = prep + (size_t)(ta + 1) * DH;
                #pragma unroll
                for (int mt = 0; mt < 4; ++mt) pf[mt] = *(const u32x2*)(p2 + mt * 16);
            }
            // carry B-frags: B[k][col=batch], lag = 2ks + (g>>1), f0 = (g&1)*8
            short8 bc[4];
            #pragma unroll
            for (int ks = 0; ks < 4; ++ks) {
                int slot = (c + ks * 2 + (g >> 1)) & 7;
                bc[ks] = *(const short8*)&carry[slot * 384 + cbase];
            }
            // acc init from pre (D layout: col=batch=m, row=hidden=g*4+r)
            f32x4 acc[4];
            #pragma unroll
            for (int mt = 0; mt < 4; ++mt) {
                acc[mt][0] = bf2f((unsigned short)(cur[mt].x & 0xFFFFu));
                acc[mt][1] = bf2f((unsigned short)(cur[mt].x >> 16));
                acc[mt][2] = bf2f((unsigned short)(cur[mt].y & 0xFFFFu));
                acc[mt][3] = bf2f((unsigned short)(cur[mt].y >> 16));
            }
            #pragma unroll
            for (int mt = 0; mt < 4; ++mt)
                #pragma unroll
                for (int ks = 0; ks < 4; ++ks)
                    acc[mt] = __builtin_amdgcn_mfma_f32_16x16x32_bf16(aw1y[mt][ks], bc[ks], acc[mt], 0, 0, 0);
            // tanh + compiler-pack + h bounce (own-wave LDS region, no barrier)
            #pragma unroll
            for (int mt = 0; mt < 4; ++mt) {
                float h0 = tanh_fast(acc[mt][0]);
                float h1 = tanh_fast(acc[mt][1]);
                float h2 = tanh_fast(acc[mt][2]);
                float h3 = tanh_fast(acc[mt][3]);
                u32x2 p = {pk_bf16(h0, h1), pk_bf16(h2, h3)};
                *(u32x2*)&hl[w * 1152 + m * 72 + mt * 16 + g * 4] = p;
            }
            // out partial: A = h [batch][k=hid], B = W2
            f32x4 oacc = {0.f, 0.f, 0.f, 0.f};
            #pragma unroll
            for (int k2 = 0; k2 < 2; ++k2) {
                short8 ha = *(const short8*)&hl[w * 1152 + m * 72 + k2 * 32 + g * 8];
                oacc = __builtin_amdgcn_mfma_f32_16x16x32_bf16(ha, bw2[k2], oacc, 0, 0, 0);
            }
            #pragma unroll
            for (int r = 0; r < 4; ++r)
                ob[w * 256 + (g * 4 + r) * 16 + m] = oacc[r];
            __syncthreads();
            if (tid < 256) {   // 4-wave reduce, write carry directly (r1-proven)
                float s = 0.0f;
                #pragma unroll
                for (int ww = 0; ww < 8; ++ww) s += ob[ww * 256 + tid];
                s += b2v;
                yreg[c] = s;                              // batched store below
                carry[c * 384 + bb * 24 + o] = f2bf(s);   // slot for y[t_abs]
            }
            __syncthreads();
        }
        if (tid < 256) {   // batched out-store: drained at next group's first barrier
            #pragma unroll
            for (int c2 = 0; c2 < 8; ++c2)
                out[((size_t)(rb + bb) * T_SZ + (t_base + t + c2 + 8)) * DY + o] = yreg[c2];
        }
    }
    // persist carry (physical slots; slot formula uses absolute t)
    for (int i = tid; i < 2048; i += 512) {
        int slot = i >> 8, rem = i & 255, b_ = rem >> 4, f = rem & 15;
        carrybf[(size_t)blockIdx.x * 2048 + i] = carry[slot * 384 + b_ * 24 + f];
    }
}

extern "C" void kernel_launch(void* const* d_in, const int* in_sizes, int n_in,
                              void* d_out, int out_size, void* d_ws, size_t ws_size,
                              hipStream_t stream) {
    const float* x  = (const float*)d_in[0];
    const float* W1 = (const float*)d_in[1];
    const float* b1 = (const float*)d_in[2];
    const float* W2 = (const float*)d_in[3];
    const float* b2 = (const float*)d_in[4];
    float* out = (float*)d_out;
    char* ws = (char*)d_ws;

    size_t ofs = 0;
    unsigned short* w1xt = (unsigned short*)(ws + ofs); ofs += (size_t)DH * KX * 2;       // 256 KB
    unsigned short* carrybf = (unsigned short*)(ws + ofs); ofs += (size_t)16 * 2048 * 2;  // 64 KB
    ofs = (ofs + 255) & ~(size_t)255;
    size_t avail = (ws_size > ofs) ? (ws_size - ofs) : 0;
    long chunkT = (long)(avail / ((size_t)B_SZ * DH * 2));
    chunkT &= ~7L;                         // phases require t_base%8==0, Tc%8==0
    if (chunkT > STEPS) chunkT = STEPS;
    if (chunkT < 8) chunkT = 8;            // assumes ws >= ~2.4 MB
    unsigned short* prebuf = (unsigned short*)(ws + ofs);

    hipLaunchKernelGGL(k_w1xt, dim3(KX), dim3(256), 0, stream, W1, w1xt);
    for (long t0 = 0; t0 < STEPS; t0 += chunkT) {
        int Tc = (int)(((STEPS - t0) < chunkT) ? (STEPS - t0) : chunkT);
        int nbt = (Tc + 255) / 256;
        hipLaunchKernelGGL(k_pre, dim3(nbt, 8, B_SZ), dim3(256), 0, stream,
                           x, w1xt, b1, prebuf, (int)t0, Tc);
        hipLaunchKernelGGL(k_seq, dim3(16), dim3(512), 0, stream,
                           W1, W2, b2, prebuf, carrybf, out, (int)t0, Tc);
    }
}

// Round 9
// 3081.498 us; speedup vs baseline: 2.4306x; 1.3616x over previous
//
#include <hip/hip_runtime.h>
#include <hip/hip_bf16.h>
#include <stdint.h>

typedef __attribute__((ext_vector_type(8))) short short8;
typedef __attribute__((ext_vector_type(4))) float f32x4;
typedef __attribute__((ext_vector_type(4))) unsigned int u32x4;
typedef __attribute__((ext_vector_type(2))) unsigned int u32x2;

#define B_SZ 256
#define T_SZ 2048
#define DX 32
#define DY 16
#define DH 512
#define KX 256   // D_I * d_x
#define KY 128   // D_O * d_y
#define STEPS 2040
#define SCALE 2.8853900817779268f   // 2*log2(e), folded into W1/b1 so tanh skips a mul

__device__ __forceinline__ unsigned short f2bf(float f) {
    unsigned int u = __float_as_uint(f);
    u += 0x7FFFu + ((u >> 16) & 1u);   // RNE
    return (unsigned short)(u >> 16);
}
__device__ __forceinline__ float bf2f(unsigned short h) {
    return __uint_as_float(((unsigned int)h) << 16);
}
// compiler-generated packed f32->bf16 (RNE)
__device__ __forceinline__ unsigned int pk_bf16(float lo, float hi) {
    __hip_bfloat162 v = __float22bfloat162_rn(make_float2(lo, hi));
    unsigned int r;
    __builtin_memcpy(&r, &v, 4);
    return r;
}
// input pre-scaled by 2*log2e: tanh(x) = 1 - 2/(exp2(s)+1)
__device__ __forceinline__ float tanh_fast(float s) {
    float e = __builtin_amdgcn_exp2f(s);
    float r = __builtin_amdgcn_rcpf(e + 1.0f);
    return __builtin_fmaf(-2.0f, r, 1.0f);
}

// ---- W1x transpose+convert+scale: w1xt[n][k] = bf16(S*W1[k][n]) ----------
__global__ void k_w1xt(const float* __restrict__ W1, unsigned short* __restrict__ w1xt) {
    int k = blockIdx.x;
    for (int h = 0; h < 2; ++h) {
        int n = threadIdx.x + h * 256;
        w1xt[(size_t)n * KX + k] = f2bf(W1[(size_t)k * DH + n] * SCALE);
    }
}

// ---- pre[b][t_rel][n] = bf16( S*(x[b,t:t+8,:]flat . W1x[:,n] + b1[n]) ) --
__global__ __launch_bounds__(256, 2) void k_pre(
    const float* __restrict__ x, const unsigned short* __restrict__ w1xt,
    const float* __restrict__ b1, unsigned short* __restrict__ pre,
    int t_base, int Tc)
{
    __shared__ __align__(16) unsigned short xl[264 * 40];
    __shared__ __align__(16) unsigned short bl[64 * 256];
    const int tid = threadIdx.x;
    const int b = blockIdx.z;
    const int t0_rel = blockIdx.x * 256;
    const int n0 = blockIdx.y * 64;

    for (int idx = tid; idx < 264 * 2; idx += 256) {
        int r = idx >> 1, half = idx & 1;
        int t = t_base + t0_rel + r; if (t > T_SZ - 1) t = T_SZ - 1;
        const float* src = x + ((size_t)b * T_SZ + t) * DX + half * 16;
        unsigned int u[8];
        #pragma unroll
        for (int q = 0; q < 4; ++q) {
            float4 v = *(const float4*)(src + q * 4);
            u[2*q]   = pk_bf16(v.x, v.y);
            u[2*q+1] = pk_bf16(v.z, v.w);
        }
        u32x4 w0 = {u[0], u[1], u[2], u[3]};
        u32x4 w1 = {u[4], u[5], u[6], u[7]};
        *(u32x4*)&xl[r * 40 + half * 16]     = w0;
        *(u32x4*)&xl[r * 40 + half * 16 + 8] = w1;
    }
    for (int idx = tid; idx < 64 * 32; idx += 256) {
        int n = idx >> 5, c = idx & 31;
        u32x4 v = *(const u32x4*)&w1xt[(size_t)(n0 + n) * KX + c * 8];
        *(u32x4*)&bl[n * 256 + ((c ^ (n & 7))) * 8] = v;
    }
    const int l = tid & 63, w = tid >> 6;
    const int m = l & 15, g = l >> 4;
    const int wm = w >> 1, wn = w & 1;
    float b1v[2];
    #pragma unroll
    for (int nt = 0; nt < 2; ++nt) b1v[nt] = b1[n0 + wn * 32 + nt * 16 + m] * SCALE;
    __syncthreads();

    f32x4 acc[8][2];
    #pragma unroll
    for (int mt = 0; mt < 8; ++mt)
        #pragma unroll
        for (int nt = 0; nt < 2; ++nt) { f32x4 z = {0,0,0,0}; acc[mt][nt] = z; }

    #pragma unroll
    for (int ks = 0; ks < 8; ++ks) {
        short8 bfr[2];
        #pragma unroll
        for (int nt = 0; nt < 2; ++nt) {
            int nl = wn * 32 + nt * 16 + m;
            bfr[nt] = *(const short8*)&bl[nl * 256 + ((ks * 4 + g) ^ (nl & 7)) * 8];
        }
        #pragma unroll
        for (int mt = 0; mt < 8; ++mt) {
            int rowt = wm * 128 + mt * 16 + m;
            short8 afr = *(const short8*)&xl[(rowt + ks) * 40 + g * 8];
            #pragma unroll
            for (int nt = 0; nt < 2; ++nt)
                acc[mt][nt] = __builtin_amdgcn_mfma_f32_16x16x32_bf16(afr, bfr[nt], acc[mt][nt], 0, 0, 0);
        }
    }
    #pragma unroll
    for (int mt = 0; mt < 8; ++mt) {
        #pragma unroll
        for (int nt = 0; nt < 2; ++nt) {
            int n_g = n0 + wn * 32 + nt * 16 + m;
            #pragma unroll
            for (int r = 0; r < 4; ++r) {
                int t_rel = t0_rel + wm * 128 + mt * 16 + g * 4 + r;
                if (t_rel < Tc)
                    pre[((size_t)b * Tc + t_rel) * DH + n_g] = f2bf(acc[mt][nt][r] + b1v[nt]);
            }
        }
    }
}

// ---- sequential NARX: 16 blocks x 16 batch rows, 512 thr (8 waves x 64 hid)
// ROUND-1 STRUCTURE VERBATIM: rolled t-loop (runtime slot &7), LDS carry ring,
// rolling 1-step prefetch, 4-wave reduce writing carry + out per step, two
// __syncthreads, launch_bounds(512,2). Only arithmetic-local deltas vs r1:
// SCALE folded into W1/b1 (tanh loses its mul) and compiler-path pk_bf16.
__global__ __launch_bounds__(512, 2) void k_seq(
    const float* __restrict__ W1, const float* __restrict__ W2,
    const float* __restrict__ b2, const unsigned short* __restrict__ pre,
    unsigned short* __restrict__ carrybf, float* __restrict__ out,
    int t_base, int Tc)
{
    __shared__ __align__(16) unsigned short carry[8 * 16 * 24]; // [slot][batch][16+8pad]
    __shared__ __align__(16) unsigned short hl[8 * 16 * 72];    // [wave][batch][64+8pad]
    __shared__ float ob[8 * 16 * 16];                           // [wave][o][batch]
    const int tid = threadIdx.x;
    const int l = tid & 63, w = tid >> 6;
    const int m = l & 15, g = l >> 4;
    const int rb = blockIdx.x * 16;
    const int hb = w * 64;

    // static A-frags of S*W1y^T: A[row=hidden][k], k = lag*16+f
    short8 aw1y[4][4];
    #pragma unroll
    for (int mt = 0; mt < 4; ++mt)
        #pragma unroll
        for (int ks = 0; ks < 4; ++ks) {
            short8 f;
            #pragma unroll
            for (int j = 0; j < 8; ++j)
                f[j] = (short)f2bf(W1[(size_t)(KX + ks * 32 + g * 8 + j) * DH + hb + mt * 16 + m] * SCALE);
            aw1y[mt][ks] = f;
        }
    // static B-frags of W2: B[k=hidden][col=o]  (NOT scaled)
    short8 bw2[2];
    #pragma unroll
    for (int k2 = 0; k2 < 2; ++k2) {
        short8 f;
        #pragma unroll
        for (int j = 0; j < 8; ++j)
            f[j] = (short)f2bf(W2[(size_t)(hb + k2 * 32 + g * 8 + j) * DY + m]);
        bw2[k2] = f;
    }
    float b2v = b2[tid & 15];

    // carry init (ring buffer keyed on absolute t)
    if (t_base == 0) {
        for (int i = tid; i < 8 * 16 * 24; i += 512) carry[i] = 0;
        for (int i = tid; i < 16 * 8 * 16; i += 512) {   // zero y_pred[:, 0:8, :]
            int bb = i >> 7, rem = i & 127, t = rem >> 4, o = rem & 15;
            out[((size_t)(rb + bb) * T_SZ + t) * DY + o] = 0.0f;
        }
    } else {
        for (int i = tid; i < 2048; i += 512) {
            int slot = i >> 8, rem = i & 255, bb = rem >> 4, f = rem & 15;
            carry[slot * 384 + bb * 24 + f] = carrybf[(size_t)blockIdx.x * 2048 + i];
        }
    }
    __syncthreads();

    const unsigned short* prep = pre + ((size_t)(rb + m) * Tc) * DH + hb + g * 4;
    u32x2 pf[4];
    #pragma unroll
    for (int mt = 0; mt < 4; ++mt) pf[mt] = *(const u32x2*)(prep + mt * 16);

    const int cbase = m * 24 + (g & 1) * 8;

    for (int t = 0; t < Tc; ++t) {
        const int t_abs = t_base + t;
        u32x2 cur[4];
        #pragma unroll
        for (int mt = 0; mt < 4; ++mt) cur[mt] = pf[mt];
        if (t + 1 < Tc) {   // prefetch next step's pre
            const unsigned short* p2 = prep + (size_t)(t + 1) * DH;
            #pragma unroll
            for (int mt = 0; mt < 4; ++mt) pf[mt] = *(const u32x2*)(p2 + mt * 16);
        }
        // carry B-frags: B[k][col=batch], lag = 2ks + (g>>1), f0 = (g&1)*8
        short8 bc[4];
        #pragma unroll
        for (int ks = 0; ks < 4; ++ks) {
            int slot = (t_abs + ks * 2 + (g >> 1)) & 7;
            bc[ks] = *(const short8*)&carry[slot * 384 + cbase];
        }
        // acc init from pre (D layout: col=batch=m, row=hidden=g*4+r)
        f32x4 acc[4];
        #pragma unroll
        for (int mt = 0; mt < 4; ++mt) {
            acc[mt][0] = bf2f((unsigned short)(cur[mt].x & 0xFFFFu));
            acc[mt][1] = bf2f((unsigned short)(cur[mt].x >> 16));
            acc[mt][2] = bf2f((unsigned short)(cur[mt].y & 0xFFFFu));
            acc[mt][3] = bf2f((unsigned short)(cur[mt].y >> 16));
        }
        #pragma unroll
        for (int mt = 0; mt < 4; ++mt)
            #pragma unroll
            for (int ks = 0; ks < 4; ++ks)
                acc[mt] = __builtin_amdgcn_mfma_f32_16x16x32_bf16(aw1y[mt][ks], bc[ks], acc[mt], 0, 0, 0);
        // tanh, pack bf16 (compiler path), write h to own wave's LDS region
        #pragma unroll
        for (int mt = 0; mt < 4; ++mt) {
            float h0 = tanh_fast(acc[mt][0]);
            float h1 = tanh_fast(acc[mt][1]);
            float h2 = tanh_fast(acc[mt][2]);
            float h3 = tanh_fast(acc[mt][3]);
            u32x2 p = {pk_bf16(h0, h1), pk_bf16(h2, h3)};
            *(u32x2*)&hl[w * 1152 + m * 72 + mt * 16 + g * 4] = p;
        }
        // out-GEMM: A = h [batch][k=hid], B = W2; D: col=o, row=batch
        f32x4 oacc = {0, 0, 0, 0};
        #pragma unroll
        for (int k2 = 0; k2 < 2; ++k2) {
            short8 ha = *(const short8*)&hl[w * 1152 + m * 72 + k2 * 32 + g * 8];
            oacc = __builtin_amdgcn_mfma_f32_16x16x32_bf16(ha, bw2[k2], oacc, 0, 0, 0);
        }
        #pragma unroll
        for (int r = 0; r < 4; ++r)
            ob[w * 256 + (g * 4 + r) * 16 + m] = oacc[r];
        __syncthreads();
        if (tid < 256) {
            float s = 0.0f;
            #pragma unroll
            for (int ww = 0; ww < 8; ++ww) s += ob[ww * 256 + tid];
            s += b2v;
            int bb = tid >> 4, o = tid & 15;
            out[((size_t)(rb + bb) * T_SZ + (t_abs + 8)) * DY + o] = s;
            carry[(t_abs & 7) * 384 + bb * 24 + o] = f2bf(s);  // slot for y[t_abs+8]
        }
        __syncthreads();
    }
    // persist carry (physical slots; slot formula uses absolute t)
    for (int i = tid; i < 2048; i += 512) {
        int slot = i >> 8, rem = i & 255, bb = rem >> 4, f = rem & 15;
        carrybf[(size_t)blockIdx.x * 2048 + i] = carry[slot * 384 + bb * 24 + f];
    }
}

extern "C" void kernel_launch(void* const* d_in, const int* in_sizes, int n_in,
                              void* d_out, int out_size, void* d_ws, size_t ws_size,
                              hipStream_t stream) {
    const float* x  = (const float*)d_in[0];
    const float* W1 = (const float*)d_in[1];
    const float* b1 = (const float*)d_in[2];
    const float* W2 = (const float*)d_in[3];
    const float* b2 = (const float*)d_in[4];
    float* out = (float*)d_out;
    char* ws = (char*)d_ws;

    size_t ofs = 0;
    unsigned short* w1xt = (unsigned short*)(ws + ofs); ofs += (size_t)DH * KX * 2;       // 256 KB
    unsigned short* carrybf = (unsigned short*)(ws + ofs); ofs += (size_t)16 * 2048 * 2;  // 64 KB
    ofs = (ofs + 255) & ~(size_t)255;
    size_t avail = (ws_size > ofs) ? (ws_size - ofs) : 0;
    long chunkT = (long)(avail / ((size_t)B_SZ * DH * 2));   // steps of pre that fit in ws
    if (chunkT > STEPS) chunkT = STEPS;
    if (chunkT < 1) chunkT = 1;   // assumes ws >= ~0.5 MB
    unsigned short* prebuf = (unsigned short*)(ws + ofs);

    hipLaunchKernelGGL(k_w1xt, dim3(KX), dim3(256), 0, stream, W1, w1xt);
    for (long t0 = 0; t0 < STEPS; t0 += chunkT) {
        int Tc = (int)(((STEPS - t0) < chunkT) ? (STEPS - t0) : chunkT);
        int nbt = (Tc + 255) / 256;
        hipLaunchKernelGGL(k_pre, dim3(nbt, 8, B_SZ), dim3(256), 0, stream,
                           x, w1xt, b1, prebuf, (int)t0, Tc);
        hipLaunchKernelGGL(k_seq, dim3(16), dim3(512), 0, stream,
                           W1, W2, b2, prebuf, carrybf, out, (int)t0, Tc);
    }
}

// Round 10
// 2524.549 us; speedup vs baseline: 2.9668x; 1.2206x over previous
//
#include <hip/hip_runtime.h>
#include <hip/hip_bf16.h>
#include <stdint.h>

typedef __attribute__((ext_vector_type(8))) short short8;
typedef __attribute__((ext_vector_type(4))) float f32x4;
typedef __attribute__((ext_vector_type(4))) unsigned int u32x4;
typedef __attribute__((ext_vector_type(2))) unsigned int u32x2;

#define B_SZ 256
#define T_SZ 2048
#define DX 32
#define DY 16
#define DH 512
#define KX 256   // D_I * d_x
#define KY 128   // D_O * d_y
#define STEPS 2040
#define SCALE 2.8853900817779268f   // 2*log2(e), folded into W1/b1 so tanh skips a mul

// lgkm-only barrier: LDS ordering preserved; global loads/stores stay in
// flight (no vmcnt(0) drain — the __syncthreads stall, m97). All LDS reads
// here are compiler-generated, so MFMA deps stay dataflow-tracked (rule 18 n/a).
#define BARRIER() asm volatile("s_waitcnt lgkmcnt(0)\n\ts_barrier" ::: "memory")

__device__ __forceinline__ unsigned short f2bf(float f) {
    unsigned int u = __float_as_uint(f);
    u += 0x7FFFu + ((u >> 16) & 1u);   // RNE
    return (unsigned short)(u >> 16);
}
__device__ __forceinline__ float bf2f(unsigned short h) {
    return __uint_as_float(((unsigned int)h) << 16);
}
// compiler-generated packed f32->bf16 (RNE)
__device__ __forceinline__ unsigned int pk_bf16(float lo, float hi) {
    __hip_bfloat162 v = __float22bfloat162_rn(make_float2(lo, hi));
    unsigned int r;
    __builtin_memcpy(&r, &v, 4);
    return r;
}
// input pre-scaled by 2*log2e: tanh(x) = 1 - 2/(exp2(s)+1)
__device__ __forceinline__ float tanh_fast(float s) {
    float e = __builtin_amdgcn_exp2f(s);
    float r = __builtin_amdgcn_rcpf(e + 1.0f);
    return __builtin_fmaf(-2.0f, r, 1.0f);
}

// ---- W1x transpose+convert+scale: w1xt[n][k] = bf16(S*W1[k][n]) ----------
__global__ void k_w1xt(const float* __restrict__ W1, unsigned short* __restrict__ w1xt) {
    int k = blockIdx.x;
    for (int h = 0; h < 2; ++h) {
        int n = threadIdx.x + h * 256;
        w1xt[(size_t)n * KX + k] = f2bf(W1[(size_t)k * DH + n] * SCALE);
    }
}

// ---- pre[b][t_rel][n] = bf16( S*(x[b,t:t+8,:]flat . W1x[:,n] + b1[n]) ) --
__global__ __launch_bounds__(256, 2) void k_pre(
    const float* __restrict__ x, const unsigned short* __restrict__ w1xt,
    const float* __restrict__ b1, unsigned short* __restrict__ pre,
    int t_base, int Tc)
{
    __shared__ __align__(16) unsigned short xl[264 * 40];
    __shared__ __align__(16) unsigned short bl[64 * 256];
    const int tid = threadIdx.x;
    const int b = blockIdx.z;
    const int t0_rel = blockIdx.x * 256;
    const int n0 = blockIdx.y * 64;

    for (int idx = tid; idx < 264 * 2; idx += 256) {
        int r = idx >> 1, half = idx & 1;
        int t = t_base + t0_rel + r; if (t > T_SZ - 1) t = T_SZ - 1;
        const float* src = x + ((size_t)b * T_SZ + t) * DX + half * 16;
        unsigned int u[8];
        #pragma unroll
        for (int q = 0; q < 4; ++q) {
            float4 v = *(const float4*)(src + q * 4);
            u[2*q]   = pk_bf16(v.x, v.y);
            u[2*q+1] = pk_bf16(v.z, v.w);
        }
        u32x4 w0 = {u[0], u[1], u[2], u[3]};
        u32x4 w1 = {u[4], u[5], u[6], u[7]};
        *(u32x4*)&xl[r * 40 + half * 16]     = w0;
        *(u32x4*)&xl[r * 40 + half * 16 + 8] = w1;
    }
    for (int idx = tid; idx < 64 * 32; idx += 256) {
        int n = idx >> 5, c = idx & 31;
        u32x4 v = *(const u32x4*)&w1xt[(size_t)(n0 + n) * KX + c * 8];
        *(u32x4*)&bl[n * 256 + ((c ^ (n & 7))) * 8] = v;
    }
    const int l = tid & 63, w = tid >> 6;
    const int m = l & 15, g = l >> 4;
    const int wm = w >> 1, wn = w & 1;
    float b1v[2];
    #pragma unroll
    for (int nt = 0; nt < 2; ++nt) b1v[nt] = b1[n0 + wn * 32 + nt * 16 + m] * SCALE;
    __syncthreads();

    f32x4 acc[8][2];
    #pragma unroll
    for (int mt = 0; mt < 8; ++mt)
        #pragma unroll
        for (int nt = 0; nt < 2; ++nt) { f32x4 z = {0,0,0,0}; acc[mt][nt] = z; }

    #pragma unroll
    for (int ks = 0; ks < 8; ++ks) {
        short8 bfr[2];
        #pragma unroll
        for (int nt = 0; nt < 2; ++nt) {
            int nl = wn * 32 + nt * 16 + m;
            bfr[nt] = *(const short8*)&bl[nl * 256 + ((ks * 4 + g) ^ (nl & 7)) * 8];
        }
        #pragma unroll
        for (int mt = 0; mt < 8; ++mt) {
            int rowt = wm * 128 + mt * 16 + m;
            short8 afr = *(const short8*)&xl[(rowt + ks) * 40 + g * 8];
            #pragma unroll
            for (int nt = 0; nt < 2; ++nt)
                acc[mt][nt] = __builtin_amdgcn_mfma_f32_16x16x32_bf16(afr, bfr[nt], acc[mt][nt], 0, 0, 0);
        }
    }
    #pragma unroll
    for (int mt = 0; mt < 8; ++mt) {
        #pragma unroll
        for (int nt = 0; nt < 2; ++nt) {
            int n_g = n0 + wn * 32 + nt * 16 + m;
            #pragma unroll
            for (int r = 0; r < 4; ++r) {
                int t_rel = t0_rel + wm * 128 + mt * 16 + g * 4 + r;
                if (t_rel < Tc)
                    pre[((size_t)b * Tc + t_rel) * DH + n_g] = f2bf(acc[mt][nt][r] + b1v[nt]);
            }
        }
    }
}

// ---- sequential NARX: 16 blocks x 16 batch rows, 512 thr (8 waves x 64 hid)
// r9 structure verbatim (rolled t-loop, LDS carry ring, rolling prefetch,
// 4-wave reduce, launch_bounds(512,2)) with ONE mechanism change: the two
// in-loop __syncthreads become lgkm-only barriers, so the per-step prefetch
// and out-stores are never vmcnt(0)-drained. Reducer writes carry before out.
__global__ __launch_bounds__(512, 2) void k_seq(
    const float* __restrict__ W1, const float* __restrict__ W2,
    const float* __restrict__ b2, const unsigned short* __restrict__ pre,
    unsigned short* __restrict__ carrybf, float* __restrict__ out,
    int t_base, int Tc)
{
    __shared__ __align__(16) unsigned short carry[8 * 16 * 24]; // [slot][batch][16+8pad]
    __shared__ __align__(16) unsigned short hl[8 * 16 * 72];    // [wave][batch][64+8pad]
    __shared__ float ob[8 * 16 * 16];                           // [wave][batch][o]
    const int tid = threadIdx.x;
    const int l = tid & 63, w = tid >> 6;
    const int m = l & 15, g = l >> 4;
    const int rb = blockIdx.x * 16;
    const int hb = w * 64;

    // static A-frags of S*W1y^T: A[row=hidden][k], k = lag*16+f
    short8 aw1y[4][4];
    #pragma unroll
    for (int mt = 0; mt < 4; ++mt)
        #pragma unroll
        for (int ks = 0; ks < 4; ++ks) {
            short8 f;
            #pragma unroll
            for (int j = 0; j < 8; ++j)
                f[j] = (short)f2bf(W1[(size_t)(KX + ks * 32 + g * 8 + j) * DH + hb + mt * 16 + m] * SCALE);
            aw1y[mt][ks] = f;
        }
    // static B-frags of W2: B[k=hidden][col=o]  (NOT scaled)
    short8 bw2[2];
    #pragma unroll
    for (int k2 = 0; k2 < 2; ++k2) {
        short8 f;
        #pragma unroll
        for (int j = 0; j < 8; ++j)
            f[j] = (short)f2bf(W2[(size_t)(hb + k2 * 32 + g * 8 + j) * DY + m]);
        bw2[k2] = f;
    }
    float b2v = b2[tid & 15];

    // carry init (ring buffer keyed on absolute t)
    if (t_base == 0) {
        for (int i = tid; i < 8 * 16 * 24; i += 512) carry[i] = 0;
        for (int i = tid; i < 16 * 8 * 16; i += 512) {   // zero y_pred[:, 0:8, :]
            int bb = i >> 7, rem = i & 127, t = rem >> 4, o = rem & 15;
            out[((size_t)(rb + bb) * T_SZ + t) * DY + o] = 0.0f;
        }
    } else {
        for (int i = tid; i < 2048; i += 512) {
            int slot = i >> 8, rem = i & 255, bb = rem >> 4, f = rem & 15;
            carry[slot * 384 + bb * 24 + f] = carrybf[(size_t)blockIdx.x * 2048 + i];
        }
    }
    __syncthreads();

    const unsigned short* prep = pre + ((size_t)(rb + m) * Tc) * DH + hb + g * 4;
    u32x2 pf[4];
    #pragma unroll
    for (int mt = 0; mt < 4; ++mt) pf[mt] = *(const u32x2*)(prep + mt * 16);

    const int cbase = m * 24 + (g & 1) * 8;

    for (int t = 0; t < Tc; ++t) {
        const int t_abs = t_base + t;
        u32x2 cur[4];
        #pragma unroll
        for (int mt = 0; mt < 4; ++mt) cur[mt] = pf[mt];
        if (t + 1 < Tc) {   // prefetch next step's pre (never drained in-loop)
            const unsigned short* p2 = prep + (size_t)(t + 1) * DH;
            #pragma unroll
            for (int mt = 0; mt < 4; ++mt) pf[mt] = *(const u32x2*)(p2 + mt * 16);
        }
        // carry B-frags: B[k][col=batch], lag = 2ks + (g>>1), f0 = (g&1)*8
        short8 bc[4];
        #pragma unroll
        for (int ks = 0; ks < 4; ++ks) {
            int slot = (t_abs + ks * 2 + (g >> 1)) & 7;
            bc[ks] = *(const short8*)&carry[slot * 384 + cbase];
        }
        // acc init from pre (D layout: col=batch=m, row=hidden=g*4+r)
        f32x4 acc[4];
        #pragma unroll
        for (int mt = 0; mt < 4; ++mt) {
            acc[mt][0] = bf2f((unsigned short)(cur[mt].x & 0xFFFFu));
            acc[mt][1] = bf2f((unsigned short)(cur[mt].x >> 16));
            acc[mt][2] = bf2f((unsigned short)(cur[mt].y & 0xFFFFu));
            acc[mt][3] = bf2f((unsigned short)(cur[mt].y >> 16));
        }
        #pragma unroll
        for (int mt = 0; mt < 4; ++mt)
            #pragma unroll
            for (int ks = 0; ks < 4; ++ks)
                acc[mt] = __builtin_amdgcn_mfma_f32_16x16x32_bf16(aw1y[mt][ks], bc[ks], acc[mt], 0, 0, 0);
        // tanh, pack bf16 (compiler path), write h to own wave's LDS region
        #pragma unroll
        for (int mt = 0; mt < 4; ++mt) {
            float h0 = tanh_fast(acc[mt][0]);
            float h1 = tanh_fast(acc[mt][1]);
            float h2 = tanh_fast(acc[mt][2]);
            float h3 = tanh_fast(acc[mt][3]);
            u32x2 p = {pk_bf16(h0, h1), pk_bf16(h2, h3)};
            *(u32x2*)&hl[w * 1152 + m * 72 + mt * 16 + g * 4] = p;
        }
        // out-GEMM: A = h [batch][k=hid], B = W2; D: col=o, row=batch
        f32x4 oacc = {0, 0, 0, 0};
        #pragma unroll
        for (int k2 = 0; k2 < 2; ++k2) {
            short8 ha = *(const short8*)&hl[w * 1152 + m * 72 + k2 * 32 + g * 8];
            oacc = __builtin_amdgcn_mfma_f32_16x16x32_bf16(ha, bw2[k2], oacc, 0, 0, 0);
        }
        #pragma unroll
        for (int r = 0; r < 4; ++r)
            ob[w * 256 + (g * 4 + r) * 16 + m] = oacc[r];
        BARRIER();
        if (tid < 256) {
            float s = 0.0f;
            #pragma unroll
            for (int ww = 0; ww < 8; ++ww) s += ob[ww * 256 + tid];
            s += b2v;
            int bb = tid >> 4, o = tid & 15;
            carry[(t_abs & 7) * 384 + bb * 24 + o] = f2bf(s);  // next step's dep first
            out[((size_t)(rb + bb) * T_SZ + (t_abs + 8)) * DY + o] = s;
        }
        BARRIER();
    }
    // persist carry (physical slots; slot formula uses absolute t)
    for (int i = tid; i < 2048; i += 512) {
        int slot = i >> 8, rem = i & 255, bb = rem >> 4, f = rem & 15;
        carrybf[(size_t)blockIdx.x * 2048 + i] = carry[slot * 384 + bb * 24 + f];
    }
}

extern "C" void kernel_launch(void* const* d_in, const int* in_sizes, int n_in,
                              void* d_out, int out_size, void* d_ws, size_t ws_size,
                              hipStream_t stream) {
    const float* x  = (const float*)d_in[0];
    const float* W1 = (const float*)d_in[1];
    const float* b1 = (const float*)d_in[2];
    const float* W2 = (const float*)d_in[3];
    const float* b2 = (const float*)d_in[4];
    float* out = (float*)d_out;
    char* ws = (char*)d_ws;

    size_t ofs = 0;
    unsigned short* w1xt = (unsigned short*)(ws + ofs); ofs += (size_t)DH * KX * 2;       // 256 KB
    unsigned short* carrybf = (unsigned short*)(ws + ofs); ofs += (size_t)16 * 2048 * 2;  // 64 KB
    ofs = (ofs + 255) & ~(size_t)255;
    size_t avail = (ws_size > ofs) ? (ws_size - ofs) : 0;
    long chunkT = (long)(avail / ((size_t)B_SZ * DH * 2));   // steps of pre that fit in ws
    if (chunkT > STEPS) chunkT = STEPS;
    if (chunkT < 1) chunkT = 1;   // assumes ws >= ~0.5 MB
    unsigned short* prebuf = (unsigned short*)(ws + ofs);

    hipLaunchKernelGGL(k_w1xt, dim3(KX), dim3(256), 0, stream, W1, w1xt);
    for (long t0 = 0; t0 < STEPS; t0 += chunkT) {
        int Tc = (int)(((STEPS - t0) < chunkT) ? (STEPS - t0) : chunkT);
        int nbt = (Tc + 255) / 256;
        hipLaunchKernelGGL(k_pre, dim3(nbt, 8, B_SZ), dim3(256), 0, stream,
                           x, w1xt, b1, prebuf, (int)t0, Tc);
        hipLaunchKernelGGL(k_seq, dim3(16), dim3(512), 0, stream,
                           W1, W2, b2, prebuf, carrybf, out, (int)t0, Tc);
    }
}